// Round 7
// baseline (328.785 us; speedup 1.0000x reference)
//
#include <hip/hip_runtime.h>
#include <hip/hip_bf16.h>
#include <stdint.h>

typedef __attribute__((ext_vector_type(4))) float f32x4;
typedef __attribute__((ext_vector_type(8))) short bf16x8;

#define D 128

__device__ inline short f2bf(float x) {
    __hip_bfloat16 h = __float2bfloat16(x);
    return __builtin_bit_cast(short, h);
}

__device__ inline bf16x8 pack8(f32x4 lo, f32x4 hi) {
    bf16x8 b;
    b[0] = f2bf(lo[0]); b[1] = f2bf(lo[1]); b[2] = f2bf(lo[2]); b[3] = f2bf(lo[3]);
    b[4] = f2bf(hi[0]); b[5] = f2bf(hi[1]); b[6] = f2bf(hi[2]); b[7] = f2bf(hi[3]);
    return b;
}

__device__ inline unsigned int pack2bf(float a, float b) {
    unsigned int ua = (unsigned int)(unsigned short)f2bf(a);
    unsigned int ub = (unsigned int)(unsigned short)f2bf(b);
    return ua | (ub << 16);
}

// ---------------- prep: pack weights (bf16 [Wself|Wneigh]) + row histogram ----------

__global__ __launch_bounds__(256)
void prep_kernel(const float* __restrict__ Wg_self, const float* __restrict__ Wg_neigh,
                 const float* __restrict__ Ws_self, const float* __restrict__ Ws_neigh,
                 short* __restrict__ Wcat,
                 const int* __restrict__ rowA, int EA,
                 const int* __restrict__ rowB, int NGoff,
                 int* __restrict__ cnt, int Etot)
{
    int t = blockIdx.x * 256 + threadIdx.x;
    if (t < 2 * 128 * 32) {
        int dir = t >> 12;
        int rem = t & 4095;
        int j = rem >> 5;
        int k = (rem & 31) * 8;
        const float* Wself  = dir ? Ws_self  : Wg_self;
        const float* Wneigh = dir ? Ws_neigh : Wg_neigh;
        const float* src = (k < 128) ? (Wself + j * D + k) : (Wneigh + j * D + (k - 128));
        f32x4 lo = *reinterpret_cast<const f32x4*>(src);
        f32x4 hi = *reinterpret_cast<const f32x4*>(src + 4);
        *reinterpret_cast<bf16x8*>(Wcat + (size_t)dir * 32768 + j * 256 + k) = pack8(lo, hi);
        return;
    }
    t -= 2 * 128 * 32;
    if (t < Etot) {
        int r = (t < EA) ? rowA[t] : (rowB[t - EA] + NGoff);
        atomicAdd(&cnt[r], 1);
    }
}

// ---------------- scans ----------------

__global__ __launch_bounds__(256)
void scan1_kernel(const int* __restrict__ cnt, int* __restrict__ part,
                  int* __restrict__ blksums, int N)
{
    __shared__ int wsum[4];
    int t = threadIdx.x;
    int base = blockIdx.x * 1024 + t * 4;
    int v0 = base + 0 < N ? cnt[base + 0] : 0;
    int v1 = base + 1 < N ? cnt[base + 1] : 0;
    int v2 = base + 2 < N ? cnt[base + 2] : 0;
    int v3 = base + 3 < N ? cnt[base + 3] : 0;
    int s = v0 + v1 + v2 + v3;
    int lane = t & 63, w = t >> 6;
    int x = s;
#pragma unroll
    for (int off = 1; off < 64; off <<= 1) {
        int y = __shfl_up(x, off);
        if (lane >= off) x += y;
    }
    if (lane == 63) wsum[w] = x;
    __syncthreads();
    int woff = 0;
    for (int i = 0; i < w; ++i) woff += wsum[i];
    int incl = x + woff;
    int excl = incl - s;
    if (base + 0 < N) part[base + 0] = excl;
    if (base + 1 < N) part[base + 1] = excl + v0;
    if (base + 2 < N) part[base + 2] = excl + v0 + v1;
    if (base + 3 < N) part[base + 3] = excl + v0 + v1 + v2;
    if (t == 255) blksums[blockIdx.x] = incl;
}

__global__ __launch_bounds__(256)
void scan2_kernel(int* __restrict__ blksums, int nb)
{
    __shared__ int wsum[4];
    int t = threadIdx.x;
    int v = t < nb ? blksums[t] : 0;
    int lane = t & 63, w = t >> 6;
    int x = v;
#pragma unroll
    for (int off = 1; off < 64; off <<= 1) {
        int y = __shfl_up(x, off);
        if (lane >= off) x += y;
    }
    if (lane == 63) wsum[w] = x;
    __syncthreads();
    int woff = 0;
    for (int i = 0; i < w; ++i) woff += wsum[i];
    int excl = x + woff - v;
    if (t < nb) blksums[t] = excl;
}

__global__ __launch_bounds__(256)
void scan3_kernel(int* __restrict__ cursor, const int* __restrict__ blksums, int N)
{
    int i = blockIdx.x * 256 + threadIdx.x;
    if (i < N) cursor[i] += blksums[i >> 10];
}

__global__ __launch_bounds__(256)
void fill2_kernel(const int* __restrict__ rowA, const int* __restrict__ colA,
                  const float* __restrict__ valA, int EA,
                  const int* __restrict__ rowB, const int* __restrict__ colB,
                  const float* __restrict__ valB, int NGoff,
                  int* __restrict__ cursor, int2* __restrict__ pairs, int Etot)
{
    int e = blockIdx.x * 256 + threadIdx.x;
    if (e >= Etot) return;
    int r, c; float v;
    if (e < EA) { r = rowA[e]; c = colA[e]; v = valA[e]; }
    else { int e2 = e - EA; r = rowB[e2] + NGoff; c = colB[e2]; v = valB[e2]; }
    int p = atomicAdd(&cursor[r], 1);
    pairs[p] = make_int2(c, __float_as_int(v));
}

// ---------------- fused gather + GEMM + relu ----------------
// 1024 thr / 16 waves / 32 rows per block; ONE row per half-wave stream.
//  - Gather: half-wave reads its row's edges directly from f32 X (f32x4 per lane,
//    512B/edge fully coalesced), predicated x4 groups (clamped idx, zeroed val) ->
//    4 independent loads in flight, no serial tail. Xself row loaded f32x4 once.
//  - Both [Xself|neigh] converted to bf16 and written to a fragment-layout LDS:
//    row = 32 entries of 16B (entry e = cols [8e,8e+8)), stored at e ^ (row&7).
//    Write: 32 lanes x 8B cover all 32 banks 2-way (free). Phase-2 ds_read_b128:
//    per quarter-wave the XOR spreads 8 bank-groups (free).
//  - Phase 2: 16 waves = 16 (row-tile x col-tile) 16x16 output tiles, 8 MFMAs each,
//    zero f32->bf16 VALU (A is already bf16 in LDS).
__global__ __launch_bounds__(1024, 8)
void fused_kernel(const float* __restrict__ X0, const float* __restrict__ X1,
                  const float* __restrict__ Xself0, float* __restrict__ out0, int n0,
                  const float* __restrict__ Xself1, float* __restrict__ out1, int n1,
                  const int* __restrict__ cnt, const int* __restrict__ endpos,
                  const int2* __restrict__ pairs, const short* __restrict__ Wcat)
{
    __shared__ bf16x8 A[32 * 32];   // 16 KiB: 32 rows x 32 entries(16B) bf16 [Xself|neigh]

    const int ROWS = 32;
    int blocks0 = (n0 + ROWS - 1) / ROWS;

    const float *X, *Xself; float* out;
    int nRows, r0base, csr0; const short* Wb;
    if ((int)blockIdx.x < blocks0) {
        X = X0; Xself = Xself0; out = out0; nRows = n0;
        r0base = blockIdx.x * ROWS; csr0 = 0; Wb = Wcat;
    } else {
        X = X1; Xself = Xself1; out = out1; nRows = n1;
        r0base = ((int)blockIdx.x - blocks0) * ROWS; csr0 = n0; Wb = Wcat + 32768;
    }

    const int tid  = threadIdx.x;
    const int wave = tid >> 6, lane = tid & 63;
    const int l15  = lane & 15, lhi = lane >> 4;
    const int l31  = lane & 31;
    const int hw   = tid >> 5;          // half-wave id == local row 0..31

    // ---- gather: one row per half-wave ----
    {
        int r = hw;
        int R = r0base + r; if (R > nRows - 1) R = nRows - 1;
        int gid = csr0 + R;
        int n = cnt[gid];
        int s = endpos[gid] - n;
        f32x4 acc = {0.f, 0.f, 0.f, 0.f};
#pragma unroll 1
        for (int j = 0; j < n; j += 4) {
            int2 p[4]; f32x4 xb[4];
#pragma unroll
            for (int u = 0; u < 4; ++u) {
                int idx = (j + u < n) ? j + u : n - 1;
                p[u] = pairs[s + idx];
            }
#pragma unroll
            for (int u = 0; u < 4; ++u)
                xb[u] = *reinterpret_cast<const f32x4*>(X + (size_t)p[u].x * D + l31 * 4);
#pragma unroll
            for (int u = 0; u < 4; ++u) {
                float v = (j + u < n) ? __int_as_float(p[u].y) : 0.f;
                acc[0] += xb[u][0] * v;
                acc[1] += xb[u][1] * v;
                acc[2] += xb[u][2] * v;
                acc[3] += xb[u][3] * v;
            }
        }
        f32x4 xs = *reinterpret_cast<const f32x4*>(Xself + (size_t)R * D + l31 * 4);
        uint2 sb  = { pack2bf(xs[0],  xs[1]),  pack2bf(xs[2],  xs[3])  };
        uint2 nbv = { pack2bf(acc[0], acc[1]), pack2bf(acc[2], acc[3]) };
        int rx = r & 7;
        int eS = (l31 >> 1) ^ rx;          // Xself entries 0..15
        int eN = 16 + ((l31 >> 1) ^ rx);   // neigh entries 16..31
        uint2* A64 = (uint2*)A;
        A64[(r * 32 + eS) * 2 + (l31 & 1)] = sb;
        A64[(r * 32 + eN) * 2 + (l31 & 1)] = nbv;
    }

    // ---- weight fragments (L2-resident; overlap other waves' gather) ----
    bf16x8 bfrag[8];
    {
        int ct = wave & 7;
        int j = ct * 16 + l15;
#pragma unroll
        for (int kb = 0; kb < 8; ++kb)
            bfrag[kb] = *reinterpret_cast<const bf16x8*>(
                Wb + (size_t)j * 256 + kb * 32 + lhi * 8);
    }

    __syncthreads();

    // ---- MFMA + relu + store: wave = (rt = wave>>3, ct = wave&7) tile ----
    {
        int rt = wave >> 3, ct = wave & 7;
        int r = rt * 16 + l15;
        int rx = r & 7;
        f32x4 acc = {0.f, 0.f, 0.f, 0.f};
#pragma unroll
        for (int kb = 0; kb < 8; ++kb) {
            int e = kb * 4 + lhi;                  // entry 0..31 (cols [8e, 8e+8))
            bf16x8 af = A[r * 32 + (e ^ rx)];
            acc = __builtin_amdgcn_mfma_f32_16x16x32_bf16(af, bfrag[kb], acc, 0, 0, 0);
        }
        // C/D layout: col = lane&15, row = (lane>>4)*4 + reg.
#pragma unroll
        for (int i = 0; i < 4; ++i) {
            int rr = r0base + rt * 16 + lhi * 4 + i;
            if (rr < nRows) {
                float v = acc[i] > 0.f ? acc[i] : 0.f;
                out[(size_t)rr * D + ct * 16 + l15] = v;
            }
        }
    }
}

// ---------------- fallback path (ws too small): atomic scatter + register GEMM ------

__global__ __launch_bounds__(256)
void scatter_edges(const float* __restrict__ X, const int* __restrict__ row,
                   const int* __restrict__ col, const float* __restrict__ val,
                   float* out, int nE)
{
    int t = blockIdx.x * 256 + threadIdx.x;
    int e = t >> 5;
    if (e >= nE) return;
    int l = t & 31;
    int r = row[e];
    int c = col[e];
    float v = val[e];
    f32x4 x = *reinterpret_cast<const f32x4*>(X + (size_t)c * D + l * 4);
    float* o = out + (size_t)r * D + l * 4;
    unsafeAtomicAdd(o + 0, x[0] * v);
    unsafeAtomicAdd(o + 1, x[1] * v);
    unsafeAtomicAdd(o + 2, x[2] * v);
    unsafeAtomicAdd(o + 3, x[3] * v);
}

__global__ __launch_bounds__(256)
void gemm_relu_fb(const float* __restrict__ Xself, const float* __restrict__ Neigh,
                  const float* __restrict__ Wself, const float* __restrict__ Wneigh,
                  float* __restrict__ out, int nRows)
{
    const int tid  = threadIdx.x;
    const int wave = tid >> 6;
    const int lane = tid & 63;
    const int l15  = lane & 15;
    const int lhi  = lane >> 4;

    bf16x8 bfrag[2][8];
#pragma unroll
    for (int n = 0; n < 2; ++n) {
        int j = wave * 32 + n * 16 + l15;
#pragma unroll
        for (int kb = 0; kb < 8; ++kb) {
            int k = kb * 32 + lhi * 8;
            const float* src = (kb < 4) ? (Wself + j * D + k)
                                        : (Wneigh + j * D + (k - 128));
            f32x4 lo = *reinterpret_cast<const f32x4*>(src);
            f32x4 hi = *reinterpret_cast<const f32x4*>(src + 4);
            bfrag[n][kb] = pack8(lo, hi);
        }
    }

    int r0base = blockIdx.x * 128;
#pragma unroll 1
    for (int it = 0; it < 8; ++it) {
        int r0 = r0base + it * 16;
        if (r0 >= nRows) break;
        const float* xrow = Xself + (size_t)(r0 + l15) * D;
        const float* nrow = Neigh + (size_t)(r0 + l15) * D;
        bf16x8 afrag[8];
#pragma unroll
        for (int kb = 0; kb < 8; ++kb) {
            const float* src = (kb < 4) ? (xrow + kb * 32 + lhi * 8)
                                        : (nrow + (kb - 4) * 32 + lhi * 8);
            f32x4 lo = *reinterpret_cast<const f32x4*>(src);
            f32x4 hi = *reinterpret_cast<const f32x4*>(src + 4);
            afrag[kb] = pack8(lo, hi);
        }
        asm volatile("s_waitcnt vmcnt(0)" ::: "memory");
        __syncthreads();

        f32x4 acc0 = {0.f, 0.f, 0.f, 0.f};
        f32x4 acc1 = {0.f, 0.f, 0.f, 0.f};
#pragma unroll
        for (int kb = 0; kb < 8; ++kb) {
            acc0 = __builtin_amdgcn_mfma_f32_16x16x32_bf16(afrag[kb], bfrag[0][kb], acc0, 0, 0, 0);
            acc1 = __builtin_amdgcn_mfma_f32_16x16x32_bf16(afrag[kb], bfrag[1][kb], acc1, 0, 0, 0);
        }
#pragma unroll
        for (int i = 0; i < 4; ++i) {
            int rr = r0 + lhi * 4 + i;
            if (rr < nRows) {
                float v0 = acc0[i] > 0.f ? acc0[i] : 0.f;
                float v1 = acc1[i] > 0.f ? acc1[i] : 0.f;
                out[(size_t)rr * D + wave * 32 + l15]      = v0;
                out[(size_t)rr * D + wave * 32 + 16 + l15] = v1;
            }
        }
    }
}

// ---------------- launch ----------------

extern "C" void kernel_launch(void* const* d_in, const int* in_sizes, int n_in,
                              void* d_out, int out_size, void* d_ws, size_t ws_size,
                              hipStream_t stream)
{
    const float* Xg_self  = (const float*)d_in[0];
    const float* Xs_self  = (const float*)d_in[1];
    const float* Xs_for_g = (const float*)d_in[2];
    const float* Xg_for_s = (const float*)d_in[3];
    const int*   row_gs   = (const int*)d_in[4];
    const int*   col_gs   = (const int*)d_in[5];
    const float* val_gs   = (const float*)d_in[6];
    const int*   row_sg   = (const int*)d_in[7];
    const int*   col_sg   = (const int*)d_in[8];
    const float* val_sg   = (const float*)d_in[9];
    const float* Wg_self  = (const float*)d_in[10];
    const float* Wg_neigh = (const float*)d_in[11];
    const float* Ws_self  = (const float*)d_in[12];
    const float* Ws_neigh = (const float*)d_in[13];

    const int NG = in_sizes[0] / D;
    const int NS = in_sizes[1] / D;
    const int E1 = in_sizes[4];
    const int E2 = in_sizes[7];
    const int N  = NG + NS;
    const int Etot = E1 + E2;

    float* out_g = (float*)d_out;
    float* out_s = out_g + (size_t)NG * D;

    // ---- workspace layout ----
    size_t off = 0;
    auto alloc = [&](size_t bytes) -> size_t {
        off = (off + 255) & ~(size_t)255;
        size_t o = off;
        off += bytes;
        return o;
    };
    size_t wcat_o   = alloc(sizeof(short) * 2 * 128 * 256);
    size_t cnt_o    = alloc(sizeof(int) * N);
    size_t cursor_o = alloc(sizeof(int) * N);
    size_t pairs_o  = alloc(sizeof(int2) * (size_t)Etot);
    size_t blk_o    = alloc(sizeof(int) * 1024);
    size_t need_bytes = off;

    char* ws = (char*)d_ws;

    if (ws_size < need_bytes) {
        // ---- fallback: atomic scatter + in-place register GEMM ----
        hipMemsetAsync(d_out, 0, (size_t)out_size * sizeof(float), stream);
        {
            long long threads = (long long)E1 * 32;
            scatter_edges<<<(int)((threads + 255) / 256), 256, 0, stream>>>(
                Xs_for_g, row_gs, col_gs, val_gs, out_g, E1);
        }
        {
            long long threads = (long long)E2 * 32;
            scatter_edges<<<(int)((threads + 255) / 256), 256, 0, stream>>>(
                Xg_for_s, row_sg, col_sg, val_sg, out_s, E2);
        }
        gemm_relu_fb<<<(NG + 127) / 128, 256, 0, stream>>>(Xg_self, out_g, Wg_self, Wg_neigh, out_g, NG);
        gemm_relu_fb<<<(NS + 127) / 128, 256, 0, stream>>>(Xs_self, out_s, Ws_self, Ws_neigh, out_s, NS);
        return;
    }

    short* wcat  = (short*)(ws + wcat_o);
    int* cnt     = (int*)(ws + cnt_o);
    int* cursor  = (int*)(ws + cursor_o);
    int2* pairs  = (int2*)(ws + pairs_o);
    int* blk     = (int*)(ws + blk_o);

    hipMemsetAsync(cnt, 0, sizeof(int) * N, stream);

    {
        long long tot = (long long)2 * 128 * 32 + Etot;
        prep_kernel<<<(int)((tot + 255) / 256), 256, 0, stream>>>(
            Wg_self, Wg_neigh, Ws_self, Ws_neigh, wcat,
            row_gs, E1, row_sg, NG, cnt, Etot);
    }

    int nb = (N + 1023) / 1024;   // 196 <= 256
    scan1_kernel<<<nb, 256, 0, stream>>>(cnt, cursor, blk, N);
    scan2_kernel<<<1, 256, 0, stream>>>(blk, nb);
    scan3_kernel<<<(N + 255) / 256, 256, 0, stream>>>(cursor, blk, N);
    fill2_kernel<<<(Etot + 255) / 256, 256, 0, stream>>>(
        row_gs, col_gs, val_gs, E1, row_sg, col_sg, val_sg, NG, cursor, pairs, Etot);

    int blocks0 = (NG + 31) / 32, blocks1 = (NS + 31) / 32;
    fused_kernel<<<blocks0 + blocks1, 1024, 0, stream>>>(
        Xs_for_g, Xg_for_s,
        Xg_self, out_g, NG,
        Xs_self, out_s, NS,
        cnt, cursor, pairs, wcat);
}